// Round 4
// baseline (15775.320 us; speedup 1.0000x reference)
//
#include <hip/hip_runtime.h>
#include <hip/hip_bf16.h>

typedef __hip_bfloat16 bf16;
typedef _Float16 hf;
typedef __attribute__((ext_vector_type(4))) float f32x4;
typedef __attribute__((ext_vector_type(8))) short short8;
typedef __attribute__((ext_vector_type(8))) _Float16 hfx8;

#define T_STEPS 100
#define BATCH   200
#define BP      256
#define NG      4096
#define NBLK    512
#define PLACE_OFF 10240000   // T*B*512

__device__ __forceinline__ void async_copy16(const bf16* gp, bf16* lp) {
    __builtin_amdgcn_global_load_lds((const __attribute__((address_space(1))) void*)gp,
                                     (__attribute__((address_space(3))) void*)lp, 16, 0, 0);
}

__device__ __forceinline__ short bf16bits(float x) {
    bf16 h = __float2bfloat16(x);
    return *(short*)&h;
}

// Sense-reversing grid barrier. Requires all blocks co-resident
// (guaranteed: 512 blocks at 2 blocks/CU x 256 CUs via launch_bounds+LDS).
__device__ __forceinline__ void grid_barrier(int* cnt, int* sense, int& local_sense) {
    __syncthreads();                 // drains vmcnt: all block stores issued
    if (threadIdx.x == 0) {
        local_sense ^= 1;
        __threadfence();             // agent fence: publish writes past per-XCD L2
        int old = __hip_atomic_fetch_add(cnt, 1, __ATOMIC_ACQ_REL, __HIP_MEMORY_SCOPE_AGENT);
        if (old == NBLK - 1) {
            __hip_atomic_store(cnt, 0, __ATOMIC_RELAXED, __HIP_MEMORY_SCOPE_AGENT);
            __hip_atomic_store(sense, local_sense, __ATOMIC_RELEASE, __HIP_MEMORY_SCOPE_AGENT);
        } else {
            while (__hip_atomic_load(sense, __ATOMIC_ACQUIRE, __HIP_MEMORY_SCOPE_AGENT) != local_sense)
                __builtin_amdgcn_s_sleep(2);
        }
    }
    __syncthreads();
}

// ================= legacy 64x64 core (k_h0 only) =================
template<int FR>
__device__ __forceinline__ void gemm_core(const bf16* __restrict__ A, const bf16* __restrict__ B,
                                          int K, int mBlk, int nBlk,
                                          bf16* As, bf16* Bs, f32x4 (&acc)[FR][FR]) {
    const int tid  = threadIdx.x;
    const int wave = tid >> 6, lane = tid & 63;
    const int waveM = (wave & 1) * (FR * 16);
    const int waveN = (wave >> 1) * (FR * 16);
    const int lrow = lane & 15;
    const int kq   = (lane >> 4) * 8;

    f32x4 zero = {0.f, 0.f, 0.f, 0.f};
#pragma unroll
    for (int mi = 0; mi < FR; ++mi)
#pragma unroll
        for (int ni = 0; ni < FR; ++ni) acc[mi][ni] = zero;

    for (int kb = 0; kb < K; kb += 64) {
#pragma unroll
        for (int i = 0; i < FR; ++i) {
            int q   = i * 256 + tid;
            int row = q >> 3, j = q & 7;
            bf16* lp = As + (size_t)(i * 256 + wave * 64) * 8;
            async_copy16(A + (size_t)(mBlk + row) * K + kb + j * 8, lp);
            bf16* lpb = Bs + (size_t)(i * 256 + wave * 64) * 8;
            async_copy16(B + (size_t)(nBlk + row) * K + kb + j * 8, lpb);
        }
        __syncthreads();
#pragma unroll
        for (int kk = 0; kk < 2; ++kk) {
            short8 af[FR], bfr[FR];
#pragma unroll
            for (int mi = 0; mi < FR; ++mi)
                af[mi] = *(const short8*)(As + (waveM + mi * 16 + lrow) * 64 + kk * 32 + kq);
#pragma unroll
            for (int ni = 0; ni < FR; ++ni)
                bfr[ni] = *(const short8*)(Bs + (waveN + ni * 16 + lrow) * 64 + kk * 32 + kq);
#pragma unroll
            for (int mi = 0; mi < FR; ++mi)
#pragma unroll
                for (int ni = 0; ni < FR; ++ni)
                    acc[mi][ni] = __builtin_amdgcn_mfma_f32_16x16x32_bf16(af[mi], bfr[ni], acc[mi][ni], 0, 0, 0);
        }
        __syncthreads();
    }
}

// ================= prep =================
__global__ __launch_bounds__(256) void k_prep(const float* __restrict__ image,
                                              const float* __restrict__ init_actv,
                                              const float* __restrict__ Wepc,
                                              const float* __restrict__ Weimg,
                                              const float* __restrict__ Whin,
                                              const float* __restrict__ Wdpc,
                                              const float* __restrict__ Wdimg,
                                              bf16* __restrict__ Wh, bf16* __restrict__ Wdec,
                                              bf16* __restrict__ Benc, bf16* __restrict__ Aenc) {
    const int NWH = 16777216;
    const int NWD = 2097152;
    const int NBE = 4194304;
    const int NAE = 262144;
    const int total = NWH + 2 * NWD + NBE + NAE;
    for (int i = blockIdx.x * blockDim.x + threadIdx.x; i < total; i += gridDim.x * blockDim.x) {
        if (i < NWH) {
            Wh[i] = __float2bfloat16(Whin[i]);
        } else if (i < NWH + NWD) {
            int j = i - NWH;
            Wdec[j] = __float2bfloat16(Wdpc[j]);
        } else if (i < NWH + 2 * NWD) {
            int j = i - NWH - NWD;
            Wdec[NWD + j] = __float2bfloat16(Wdimg[j]);
        } else if (i < NWH + 2 * NWD + NBE) {
            int j = i - NWH - 2 * NWD;
            int g = j >> 10, c = j & 1023;
            float v = (c < 512) ? Wepc[g * 512 + c] : Weimg[g * 512 + (c - 512)];
            Benc[j] = __float2bfloat16(v);
        } else {
            int j = i - NWH - 2 * NWD - NBE;
            int b = j >> 10, c = j & 1023;
            float v = 0.f;
            if (b < BATCH) v = (c < 512) ? init_actv[b * 512 + c] : image[b * 512 + (c - 512)];
            Aenc[j] = __float2bfloat16(v);
        }
    }
}

// ================= h0 =================
__global__ __launch_bounds__(256) void k_h0(const bf16* __restrict__ A, const bf16* __restrict__ B,
                                            bf16* __restrict__ H) {
    __shared__ __align__(16) bf16 As[64 * 64];
    __shared__ __align__(16) bf16 Bs[64 * 64];
    f32x4 acc[2][2];
    int mBlk = blockIdx.y * 64, nBlk = blockIdx.x * 64;
    gemm_core<2>(A, B, 1024, mBlk, nBlk, As, Bs, acc);
    int lane = threadIdx.x & 63, wave = threadIdx.x >> 6;
    int waveM = (wave & 1) * 32, waveN = (wave >> 1) * 32;
#pragma unroll
    for (int mi = 0; mi < 2; ++mi)
#pragma unroll
        for (int r = 0; r < 4; ++r) {
            int row = mBlk + waveM + mi * 16 + (lane >> 4) * 4 + r;
#pragma unroll
            for (int ni = 0; ni < 2; ++ni) {
                int col = nBlk + waveN + ni * 16 + (lane & 15);
                H[(size_t)row * NG + col] = __float2bfloat16(acc[mi][ni][r]);
            }
        }
}

// ================= persistent recurrence (manual grid barrier) =================
// 512 blocks (2/CU), 256 threads. Gemm: s = bid&7 (K-split, XCD-affine),
// rowhalf = (bid>>3)&1, colgroup = bid>>4 (32 groups of 128 cols).
// Tile 128x128, K=512 per split. Reduce: row = bid>>1, half = bid&1.
__global__ __launch_bounds__(256, 2) void k_rnn(const bf16* __restrict__ H0,
                                                const bf16* __restrict__ Wh,
                                                bf16* __restrict__ Gall,
                                                hf* __restrict__ P,
                                                const float* __restrict__ vel,
                                                const float* __restrict__ Wv,
                                                int* __restrict__ bar) {
    __shared__ __align__(16) bf16 As[128 * 64];   // 16 KB
    __shared__ __align__(16) bf16 Bs[128 * 64];   // 16 KB

    const int tid  = threadIdx.x;
    const int wave = tid >> 6, lane = tid & 63;
    const int lrow = lane & 15;
    const int kq   = lane >> 4;
    const int bid  = blockIdx.x;
    const int s       = bid & 7;
    const int rbase   = ((bid >> 3) & 1) * 128;
    const int colbase = (bid >> 4) * 128;
    const int kbase   = s * 512;
    const int waveM = (wave & 1) * 64;
    const int waveN = (wave >> 1) * 64;

    const int rrow   = bid >> 1;
    const int rcbase = (bid & 1) * 2048 + tid * 8;

    int* cnt = bar;
    int* sense = bar + 8;
    int local_sense = 0;

    for (int t = 0; t < T_STEPS; ++t) {
        const bf16* Ap = (t == 0) ? H0 : (Gall + (size_t)(t - 1) * BP * NG);

        f32x4 acc[4][4];
        f32x4 zero = {0.f, 0.f, 0.f, 0.f};
#pragma unroll
        for (int mi = 0; mi < 4; ++mi)
#pragma unroll
            for (int ni = 0; ni < 4; ++ni) acc[mi][ni] = zero;

        for (int kb = 0; kb < 512; kb += 64) {
#pragma unroll
            for (int i = 0; i < 4; ++i) {       // A: 128 rows x 8 chunks
                int q = i * 256 + tid;
                int row = q >> 3, j = q & 7;
                int jsrc = j ^ (row & 7);
                async_copy16(Ap + (size_t)(rbase + row) * NG + kbase + kb + jsrc * 8, As + q * 8);
            }
#pragma unroll
            for (int i = 0; i < 4; ++i) {       // B: 128 cols x 8 chunks
                int q = i * 256 + tid;
                int row = q >> 3, j = q & 7;
                int jsrc = j ^ (row & 7);
                async_copy16(Wh + (size_t)(colbase + row) * NG + kbase + kb + jsrc * 8, Bs + q * 8);
            }
            __syncthreads();
#pragma unroll
            for (int kk = 0; kk < 2; ++kk) {
                int cch = kk * 4 + kq;
                short8 af[4], bfv[4];
#pragma unroll
                for (int mi = 0; mi < 4; ++mi) {
                    int r = waveM + mi * 16 + lrow;
                    af[mi] = *(const short8*)(As + r * 64 + ((cch ^ (r & 7)) * 8));
                }
#pragma unroll
                for (int ni = 0; ni < 4; ++ni) {
                    int cl = waveN + ni * 16 + lrow;
                    bfv[ni] = *(const short8*)(Bs + cl * 64 + ((cch ^ (cl & 7)) * 8));
                }
#pragma unroll
                for (int mi = 0; mi < 4; ++mi)
#pragma unroll
                    for (int ni = 0; ni < 4; ++ni)
                        acc[mi][ni] = __builtin_amdgcn_mfma_f32_16x16x32_bf16(af[mi], bfv[ni], acc[mi][ni], 0, 0, 0);
            }
            __syncthreads();
        }

        hf* Pp = P + (size_t)s * BP * NG;
#pragma unroll
        for (int mi = 0; mi < 4; ++mi)
#pragma unroll
            for (int rr = 0; rr < 4; ++rr) {
                int row = rbase + waveM + mi * 16 + (lane >> 4) * 4 + rr;
#pragma unroll
                for (int ni = 0; ni < 4; ++ni) {
                    int col = colbase + waveN + ni * 16 + lrow;
                    Pp[(size_t)row * NG + col] = (hf)acc[mi][ni][rr];
                }
            }

        grid_barrier(cnt, sense, local_sense);

        {
            float v0 = 0.f, v1 = 0.f;
            if (rrow < BATCH) {
                v0 = vel[(size_t)(t * BATCH + rrow) * 2 + 0];
                v1 = vel[(size_t)(t * BATCH + rrow) * 2 + 1];
            }
            float sum[8];
#pragma unroll
            for (int j = 0; j < 8; ++j) sum[j] = 0.f;
#pragma unroll
            for (int sp = 0; sp < 8; ++sp) {
                hfx8 p = *(const hfx8*)(P + (size_t)(sp * BP + rrow) * NG + rcbase);
#pragma unroll
                for (int j = 0; j < 8; ++j) sum[j] += (float)p[j];
            }
            const f32x4* wp = (const f32x4*)(Wv + (size_t)rcbase * 2);
            f32x4 w0 = wp[0], w1 = wp[1], w2 = wp[2], w3 = wp[3];
            float o[8];
            o[0] = sum[0] + v0 * w0[0] + v1 * w0[1];
            o[1] = sum[1] + v0 * w0[2] + v1 * w0[3];
            o[2] = sum[2] + v0 * w1[0] + v1 * w1[1];
            o[3] = sum[3] + v0 * w1[2] + v1 * w1[3];
            o[4] = sum[4] + v0 * w2[0] + v1 * w2[1];
            o[5] = sum[5] + v0 * w2[2] + v1 * w2[3];
            o[6] = sum[6] + v0 * w3[0] + v1 * w3[1];
            o[7] = sum[7] + v0 * w3[2] + v1 * w3[3];
            short8 ov;
#pragma unroll
            for (int j = 0; j < 8; ++j) ov[j] = bf16bits(fmaxf(o[j], 0.f));
            *(short8*)(Gall + (size_t)t * BP * NG + (size_t)rrow * NG + rcbase) = ov;
        }

        grid_barrier(cnt, sense, local_sense);
    }
}

// ================= decode: 256x128 tile, kb=64, 4 waves (wave 128x64) =================
__global__ __launch_bounds__(256, 2) void k_decode(const bf16* __restrict__ G,
                                                   const bf16* __restrict__ Wd,
                                                   float* __restrict__ out) {
    __shared__ __align__(16) bf16 As[256 * 64];   // 32 KB
    __shared__ __align__(16) bf16 Bs[128 * 64];   // 16 KB
    const int tid = threadIdx.x;
    const int wave = tid >> 6, lane = tid & 63;
    const int lrow = lane & 15;
    const int kq = lane >> 4;
    const int mBlk = blockIdx.y * 256;
    const int nBlk = blockIdx.x * 128;
    const int waveM = (wave & 1) * 128;
    const int waveN = (wave >> 1) * 64;

    f32x4 acc[8][4];
    f32x4 zero = {0.f, 0.f, 0.f, 0.f};
#pragma unroll
    for (int mi = 0; mi < 8; ++mi)
#pragma unroll
        for (int ni = 0; ni < 4; ++ni) acc[mi][ni] = zero;

    for (int kb = 0; kb < NG; kb += 64) {
#pragma unroll
        for (int i = 0; i < 8; ++i) {            // A: 256 rows x 8 chunks
            int q = i * 256 + tid;
            int row = q >> 3, j = q & 7;
            int jsrc = j ^ (row & 7);
            async_copy16(G + (size_t)(mBlk + row) * NG + kb + jsrc * 8, As + q * 8);
        }
#pragma unroll
        for (int i = 0; i < 4; ++i) {            // B: 128 cols x 8 chunks
            int q = i * 256 + tid;
            int row = q >> 3, j = q & 7;
            int jsrc = j ^ (row & 7);
            async_copy16(Wd + (size_t)(nBlk + row) * NG + kb + jsrc * 8, Bs + q * 8);
        }
        __syncthreads();
#pragma unroll
        for (int kk = 0; kk < 2; ++kk) {
            int cch = kk * 4 + kq;
            short8 af[8], bfv[4];
#pragma unroll
            for (int mi = 0; mi < 8; ++mi) {
                int r = waveM + mi * 16 + lrow;
                af[mi] = *(const short8*)(As + r * 64 + ((cch ^ (r & 7)) * 8));
            }
#pragma unroll
            for (int ni = 0; ni < 4; ++ni) {
                int cl = waveN + ni * 16 + lrow;
                bfv[ni] = *(const short8*)(Bs + cl * 64 + ((cch ^ (cl & 7)) * 8));
            }
#pragma unroll
            for (int mi = 0; mi < 8; ++mi)
#pragma unroll
                for (int ni = 0; ni < 4; ++ni)
                    acc[mi][ni] = __builtin_amdgcn_mfma_f32_16x16x32_bf16(af[mi], bfv[ni], acc[mi][ni], 0, 0, 0);
        }
        __syncthreads();
    }

#pragma unroll
    for (int mi = 0; mi < 8; ++mi)
#pragma unroll
        for (int r = 0; r < 4; ++r) {
            int R = mBlk + waveM + mi * 16 + (lane >> 4) * 4 + r;
            int t = R >> 8, bb = R & 255;
            if (bb < BATCH) {
                size_t obase = (size_t)(t * BATCH + bb) * 512;
#pragma unroll
                for (int ni = 0; ni < 4; ++ni) {
                    int col = nBlk + waveN + ni * 16 + lrow;
                    float v = acc[mi][ni][r];
                    if (col < 512) {
                        out[obase + col] = v;
                    } else {
                        out[PLACE_OFF + obase + (col - 512)] = 1.f / (1.f + __expf(-v));
                    }
                }
            }
        }
}

extern "C" void kernel_launch(void* const* d_in, const int* in_sizes, int n_in,
                              void* d_out, int out_size, void* d_ws, size_t ws_size,
                              hipStream_t stream) {
    const float* image     = (const float*)d_in[0];
    const float* vel       = (const float*)d_in[1];
    const float* init_actv = (const float*)d_in[2];
    const float* Wepc      = (const float*)d_in[3];
    const float* Weimg     = (const float*)d_in[4];
    const float* Wv        = (const float*)d_in[5];
    const float* Whin      = (const float*)d_in[6];
    const float* Wdpc      = (const float*)d_in[7];
    const float* Wdimg     = (const float*)d_in[8];
    float* out = (float*)d_out;

    char* w = (char*)d_ws;
    bf16* Wh   = (bf16*)w; w += (size_t)16777216 * 2;    // 4096x4096
    bf16* Wdec = (bf16*)w; w += (size_t)4194304 * 2;     // 1024x4096
    bf16* Benc = (bf16*)w; w += (size_t)4194304 * 2;     // 4096x1024
    bf16* Aenc = (bf16*)w; w += (size_t)262144 * 2;      // 256x1024
    bf16* H0   = (bf16*)w; w += (size_t)(BP * NG) * 2;   // 256x4096
    hf*   P    = (hf*)w;   w += (size_t)8 * BP * NG * 2; // 8x256x4096 fp16
    bf16* Gall = (bf16*)w; w += (size_t)T_STEPS * BP * NG * 2; // 100x256x4096
    int*  bar  = (int*)w;                                 // barrier state (64 B)

    hipMemsetAsync(bar, 0, 64, stream);
    k_prep<<<4096, 256, 0, stream>>>(image, init_actv, Wepc, Weimg, Whin, Wdpc, Wdimg,
                                     Wh, Wdec, Benc, Aenc);
    k_h0<<<dim3(64, 4), 256, 0, stream>>>(Aenc, Benc, H0);
    k_rnn<<<NBLK, 256, 0, stream>>>(H0, Wh, Gall, P, vel, Wv, bar);
    k_decode<<<dim3(8, 100), 256, 0, stream>>>(Gall, Wdec, out);
}